// Round 7
// baseline (400.266 us; speedup 1.0000x reference)
//
#include <hip/hip_runtime.h>
#include <stdint.h>

#define AS1 __attribute__((address_space(1)))
#define AS3 __attribute__((address_space(3)))

typedef __bf16 bf8_t __attribute__((ext_vector_type(8)));
typedef float f4_t __attribute__((ext_vector_type(4)));

// ---------------- helpers ----------------
__device__ __forceinline__ unsigned short f2b(float f) {
  unsigned u = __builtin_bit_cast(unsigned, f);
  u += 0x7fffu + ((u >> 16) & 1u);          // RNE
  return (unsigned short)(u >> 16);
}
__device__ __forceinline__ void unpack8(uint4 u, float* dst) {
  unsigned a0 = u.x, a1 = u.y, a2 = u.z, a3 = u.w;
  dst[0] = __builtin_bit_cast(float, a0 << 16);
  dst[1] = __builtin_bit_cast(float, a0 & 0xffff0000u);
  dst[2] = __builtin_bit_cast(float, a1 << 16);
  dst[3] = __builtin_bit_cast(float, a1 & 0xffff0000u);
  dst[4] = __builtin_bit_cast(float, a2 << 16);
  dst[5] = __builtin_bit_cast(float, a2 & 0xffff0000u);
  dst[6] = __builtin_bit_cast(float, a3 << 16);
  dst[7] = __builtin_bit_cast(float, a3 & 0xffff0000u);
}

// ---------------- fused f32 -> bf16 convert for all 4 weights -------------
__global__ __launch_bounds__(256) void f2b_all(
    const float* __restrict__ w_in, const float* __restrict__ w_out,
    const float* __restrict__ w_fc, const float* __restrict__ w_proj,
    unsigned short* __restrict__ o_in, unsigned short* __restrict__ o_out,
    unsigned short* __restrict__ o_fc, unsigned short* __restrict__ o_proj) {
  const int blk = blockIdx.x;
  const float* src;
  unsigned short* dst;
  int base;
  if (blk < 3072) { src = w_in; dst = o_in; base = blk; }
  else if (blk < 4096) { src = w_out; dst = o_out; base = blk - 3072; }
  else if (blk < 8192) { src = w_fc; dst = o_fc; base = blk - 4096; }
  else { src = w_proj; dst = o_proj; base = blk - 8192; }
  const int i = (base * 256 + threadIdx.x) * 4;
  float4 v = *(const float4*)(src + i);
  union { unsigned short u[4]; uint2 d; } p;
  p.u[0] = f2b(v.x); p.u[1] = f2b(v.y); p.u[2] = f2b(v.z); p.u[3] = f2b(v.w);
  *(uint2*)(dst + i) = p.d;
}

// ---------------- LayerNorm (E=1024), f32 in -> bf16 out -------------------
// aux != null: also write aux = x (+ bias) f32 -- pre-init for split-K atomics.
__global__ __launch_bounds__(256) void ln_kernel(const float* __restrict__ x,
                                                 unsigned short* __restrict__ out,
                                                 float* __restrict__ aux,
                                                 const float* __restrict__ bias) {
  const int row = blockIdx.x, tid = threadIdx.x;
  const float* xr = x + (size_t)row * 1024;
  float4 v = ((const float4*)xr)[tid];
  if (aux) {
    float4 w = v;
    if (bias) {
      float4 bv = *(const float4*)(bias + tid * 4);
      w.x += bv.x; w.y += bv.y; w.z += bv.z; w.w += bv.w;
    }
    *(float4*)(aux + (size_t)row * 1024 + tid * 4) = w;
  }
  float s = v.x + v.y + v.z + v.w;
  float q = v.x * v.x + v.y * v.y + v.z * v.z + v.w * v.w;
  for (int o = 32; o; o >>= 1) { s += __shfl_down(s, o); q += __shfl_down(q, o); }
  __shared__ float rs[4], rq[4];
  const int w = tid >> 6;
  if ((tid & 63) == 0) { rs[w] = s; rq[w] = q; }
  __syncthreads();
  s = rs[0] + rs[1] + rs[2] + rs[3];
  q = rq[0] + rq[1] + rq[2] + rq[3];
  const float mean = s * (1.0f / 1024.0f);
  const float var = q * (1.0f / 1024.0f) - mean * mean;
  const float rstd = rsqrtf(var + 1e-5f);
  union { unsigned short u[4]; uint2 d; } p;
  p.u[0] = f2b((v.x - mean) * rstd);
  p.u[1] = f2b((v.y - mean) * rstd);
  p.u[2] = f2b((v.z - mean) * rstd);
  p.u[3] = f2b((v.w - mean) * rstd);
  *(uint2*)(out + (size_t)row * 1024 + tid * 4) = p.d;
}

// ---------------- GEMM: C[M,N] = A[M,K] @ W[N,K]^T (bf16 in, fp32 acc) ------
// BM=128 x BN tile (BN=256 or 192): 24(20) KB staged per iter for 128(96)
// MFMAs -- 2-3x the arithmetic intensity of the 64x128 tile, which was
// staging-BW bound at ~9.6 TB/s. 1D grid, bn = lin & 15 so xcd ~= lin % 8
// pins each weight n-tile to one XCD's L2. Double-buffered global_load_lds.
// EPI: 0 = store bf16; 2 = +bias, relu -> bf16; 4 = atomicAdd f32 (split-K)
template <int EPI, int BN, int SPLITK>
__global__ __launch_bounds__(256, 2) void gemm_bt(
    const unsigned short* __restrict__ A, const unsigned short* __restrict__ Bw,
    int M, int N, int K,
    const float* __restrict__ bias,
    float* __restrict__ outF, unsigned short* __restrict__ outB) {
  constexpr int BM = 128;
  constexpr int NI = BN / 32;           // n-frags per wave
  constexpr int NCH = (BM + BN) / 16;   // 16-row staging chunks per k-tile
  constexpr int PC = NCH / 4;           // chunks per wave
  __shared__ unsigned short As[2][BM * 32];
  __shared__ unsigned short Bs[2][BN * 32];
  const int lin = blockIdx.x;
  const int combo = lin & 15;
  const int bm = lin >> 4;
  const int bn = (SPLITK > 1) ? (combo >> 2) : combo;
  const int kz = (SPLITK > 1) ? (combo & 3) : 0;
  const int tid = threadIdx.x;
  const int wave = tid >> 6, lane = tid & 63;
  const int wm = (wave & 1) * 64, wn = (wave >> 1) * (BN / 2);
  const int l16 = lane & 15, quad = lane >> 4;
  const int srow = lane >> 2;
  const int scol = (lane & 3) * 8;

  const int kbeg = kz * (K / SPLITK);
  const unsigned short* Abase = A + (size_t)(bm * BM) * K + kbeg;
  const unsigned short* Bbase = Bw + (size_t)(bn * BN) * K + kbeg;

  f4_t acc[4][NI];
#pragma unroll
  for (int i = 0; i < 4; ++i)
#pragma unroll
    for (int j = 0; j < NI; ++j) acc[i][j] = (f4_t){0.f, 0.f, 0.f, 0.f};

  const int kiters = (K / SPLITK) >> 5;

  auto stage = [&](int k0, int buf) {
    const int kk = k0 * 32;
#pragma unroll
    for (int i = 0; i < PC; ++i) {
      const int c = wave * PC + i;
      if (c < BM / 16) {
        const unsigned short* ga = Abase + (size_t)(c * 16 + srow) * K + kk + scol;
        __builtin_amdgcn_global_load_lds((const AS1 void*)ga,
                                         (AS3 void*)(&As[buf][c * 512]), 16, 0, 0);
      } else {
        const int c2 = c - BM / 16;
        const unsigned short* gb = Bbase + (size_t)(c2 * 16 + srow) * K + kk + scol;
        __builtin_amdgcn_global_load_lds((const AS1 void*)gb,
                                         (AS3 void*)(&Bs[buf][c2 * 512]), 16, 0, 0);
      }
    }
  };

  stage(0, 0);
  __syncthreads();
  for (int k0 = 0; k0 < kiters; ++k0) {
    const int cur = k0 & 1;
    if (k0 + 1 < kiters) stage(k0 + 1, cur ^ 1);
    bf8_t af[4], bfr[NI];
#pragma unroll
    for (int mi = 0; mi < 4; ++mi)
      af[mi] = *(const bf8_t*)&As[cur][(wm + mi * 16 + l16) * 32 + quad * 8];
#pragma unroll
    for (int ni = 0; ni < NI; ++ni)
      bfr[ni] = *(const bf8_t*)&Bs[cur][(wn + ni * 16 + l16) * 32 + quad * 8];
#pragma unroll
    for (int mi = 0; mi < 4; ++mi)
#pragma unroll
      for (int ni = 0; ni < NI; ++ni)
        acc[mi][ni] =
            __builtin_amdgcn_mfma_f32_16x16x32_bf16(af[mi], bfr[ni], acc[mi][ni], 0, 0, 0);
    __syncthreads();  // drains next-tile loads (issued a full compute phase ago)
  }

#pragma unroll
  for (int mi = 0; mi < 4; ++mi) {
#pragma unroll
    for (int ni = 0; ni < NI; ++ni) {
      const int gm0 = bm * BM + wm + mi * 16 + quad * 4;
      const int gn = bn * BN + wn + ni * 16 + l16;
#pragma unroll
      for (int r = 0; r < 4; ++r) {
        float v = acc[mi][ni][r];
        const size_t idx = (size_t)(gm0 + r) * N + gn;
        if (EPI == 0) {
          outB[idx] = f2b(v);
        } else if (EPI == 2) {
          v += bias[gn];
          outB[idx] = f2b(fmaxf(v, 0.0f));
        } else {
          atomicAdd(&outF[idx], v);
        }
      }
    }
  }
}

// ---------------- K/V tile pre-pack ----------------
__global__ __launch_bounds__(256) void pack_kv(const unsigned short* __restrict__ qkv,
                                               unsigned short* __restrict__ Kp,
                                               unsigned short* __restrict__ Vp) {
  const int lin = blockIdx.x;
  const int kt = lin & 31, h = (lin >> 5) & 15, b = lin >> 9;
  const int tid = threadIdx.x;
  __shared__ unsigned short Vs[64 * 72];
  const size_t rowbase = (size_t)(b * 2048 + kt * 64) * 3072 + h * 64;
  unsigned short* Kt = Kp + (size_t)lin * 4096;
  unsigned short* Vt = Vp + (size_t)lin * 4096;

  const int r0 = tid >> 3, cin = tid & 7;
#pragma unroll
  for (int it = 0; it < 2; ++it) {
    const int r = r0 + it * 32;
    uint4 ku = *(const uint4*)(qkv + rowbase + (size_t)r * 3072 + 1024 + cin * 8);
    float f[8]; unpack8(ku, f);
    union { unsigned short us[8]; uint4 v; } pk;
#pragma unroll
    for (int j = 0; j < 8; ++j) pk.us[j] = f2b(f[j] * 0.125f);
    *(uint4*)(Kt + (size_t)(r * 8 + (cin ^ (r & 7))) * 8) = pk.v;
    uint4 vu = *(const uint4*)(qkv + rowbase + (size_t)r * 3072 + 2048 + cin * 8);
    *(uint4*)&Vs[r * 72 + cin * 8] = vu;
  }
  __syncthreads();
#pragma unroll
  for (int oc2 = 0; oc2 < 2; ++oc2) {
    const int oc = tid * 2 + oc2;
    const int d = oc >> 3, c = oc & 7;
    const int k0 = 8 * (c ^ (d & 7));
    union { unsigned short us[8]; uint4 v; } pk;
#pragma unroll
    for (int j = 0; j < 8; ++j) pk.us[j] = Vs[(k0 + j) * 72 + d];
    *(uint4*)(Vt + (size_t)oc * 8) = pk.v;
  }
}

// ---------------- MFMA causal flash attention ----------------
__global__ __launch_bounds__(256, 4) void attn_kernel(const unsigned short* __restrict__ qkv,
                                                      const unsigned short* __restrict__ Kp,
                                                      const unsigned short* __restrict__ Vp,
                                                      unsigned short* __restrict__ o) {
  const int lin = blockIdx.x;
  const int b = lin & 1, h = (lin >> 1) & 15, tq = lin >> 5;
  const int tid = threadIdx.x;
  const int wave = tid >> 6, lane = tid & 63;
  const int l15 = lane & 15, quad = lane >> 4;

  __shared__ __align__(16) unsigned short Ks[64 * 64];
  __shared__ __align__(16) unsigned short Vt[64 * 64];
  __shared__ __align__(16) unsigned short Ps[64 * 72];

  bf8_t qf[2];
  {
    const int qrow = b * 2048 + tq * 64 + wave * 16 + l15;
#pragma unroll
    for (int s = 0; s < 2; ++s) {
      union { uint4 u; bf8_t v; } pk;
      pk.u = *(const uint4*)(qkv + (size_t)qrow * 3072 + h * 64 + s * 32 + quad * 8);
      qf[s] = pk.v;
    }
  }

  float m_s = -1e30f, l_s = 0.f;
  f4_t O[4];
#pragma unroll
  for (int j = 0; j < 4; ++j) O[j] = (f4_t){0.f, 0.f, 0.f, 0.f};

  const int qw0 = tq * 64 + wave * 16;
  const int swz = (l15 & 7) * 8;
  const size_t tile0 = (size_t)((b * 16 + h) * 32) * 4096;

  for (int kt = 0; kt <= tq; ++kt) {
    __syncthreads();
    const unsigned short* Ktile = Kp + tile0 + (size_t)kt * 4096;
    const unsigned short* Vtile = Vp + tile0 + (size_t)kt * 4096;
#pragma unroll
    for (int i = 0; i < 2; ++i) {
      const int seg = wave * 2 + i;
      __builtin_amdgcn_global_load_lds((const AS1 void*)(Ktile + seg * 512 + lane * 8),
                                       (AS3 void*)(Ks + seg * 512), 16, 0, 0);
      __builtin_amdgcn_global_load_lds((const AS1 void*)(Vtile + seg * 512 + lane * 8),
                                       (AS3 void*)(Vt + seg * 512), 16, 0, 0);
    }
    __syncthreads();

    f4_t S[4];
#pragma unroll
    for (int mi = 0; mi < 4; ++mi) S[mi] = (f4_t){0.f, 0.f, 0.f, 0.f};
#pragma unroll
    for (int s = 0; s < 2; ++s)
#pragma unroll
      for (int mi = 0; mi < 4; ++mi) {
        bf8_t kf = *(const bf8_t*)&Ks[(mi * 16 + l15) * 64 + (((4 * s + quad) * 8) ^ swz)];
        S[mi] = __builtin_amdgcn_mfma_f32_16x16x32_bf16(kf, qf[s], S[mi], 0, 0, 0);
      }

    if (kt == tq) {
#pragma unroll
      for (int mi = 0; mi < 4; ++mi)
#pragma unroll
        for (int r = 0; r < 4; ++r) {
          const int kg = kt * 64 + mi * 16 + quad * 4 + r;
          const int qg = qw0 + l15;
          if (kg > qg) S[mi][r] = -1e30f;
        }
    }

    float mx = -1e30f;
#pragma unroll
    for (int mi = 0; mi < 4; ++mi)
#pragma unroll
      for (int r = 0; r < 4; ++r) mx = fmaxf(mx, S[mi][r]);
    mx = fmaxf(mx, __shfl_xor(mx, 16));
    mx = fmaxf(mx, __shfl_xor(mx, 32));
    const float mn = fmaxf(m_s, mx);
    const float alpha = __expf(m_s - mn);
    float sum = 0.f;
#pragma unroll
    for (int mi = 0; mi < 4; ++mi)
#pragma unroll
      for (int r = 0; r < 4; ++r) {
        const float p = __expf(S[mi][r] - mn);
        S[mi][r] = p;
        sum += p;
      }
    sum += __shfl_xor(sum, 16);
    sum += __shfl_xor(sum, 32);
    m_s = mn;
    l_s = l_s * alpha + sum;
#pragma unroll
    for (int mi = 0; mi < 4; ++mi) {
      uint2 w2;
      w2.x = (unsigned)f2b(S[mi][0]) | ((unsigned)f2b(S[mi][1]) << 16);
      w2.y = (unsigned)f2b(S[mi][2]) | ((unsigned)f2b(S[mi][3]) << 16);
      *(uint2*)&Ps[(wave * 16 + l15) * 72 + mi * 16 + quad * 4] = w2;
    }

    bf8_t pf[2], vf[4][2];
#pragma unroll
    for (int s = 0; s < 2; ++s)
      pf[s] = *(const bf8_t*)&Ps[(wave * 16 + l15) * 72 + s * 32 + quad * 8];
#pragma unroll
    for (int n4 = 0; n4 < 4; ++n4)
#pragma unroll
      for (int s = 0; s < 2; ++s)
        vf[n4][s] = *(const bf8_t*)&Vt[(n4 * 16 + l15) * 64 + (((4 * s + quad) * 8) ^ swz)];
    float ar[4];
#pragma unroll
    for (int r = 0; r < 4; ++r) ar[r] = __shfl(alpha, quad * 4 + r);
#pragma unroll
    for (int n4 = 0; n4 < 4; ++n4) {
#pragma unroll
      for (int r = 0; r < 4; ++r) O[n4][r] *= ar[r];
#pragma unroll
      for (int s = 0; s < 2; ++s)
        O[n4] = __builtin_amdgcn_mfma_f32_16x16x32_bf16(pf[s], vf[n4][s], O[n4], 0, 0, 0);
    }
  }

  const float rc = 1.0f / l_s;
  float rr[4];
#pragma unroll
  for (int r = 0; r < 4; ++r) rr[r] = __shfl(rc, quad * 4 + r);
#pragma unroll
  for (int n4 = 0; n4 < 4; ++n4)
#pragma unroll
    for (int r = 0; r < 4; ++r) {
      const int qg = tq * 64 + wave * 16 + quad * 4 + r;
      o[(size_t)(b * 2048 + qg) * 1024 + h * 64 + n4 * 16 + l15] = f2b(O[n4][r] * rr[r]);
    }
}

// ---------------- launcher ----------------
extern "C" void kernel_launch(void* const* d_in, const int* in_sizes, int n_in,
                              void* d_out, int out_size, void* d_ws, size_t ws_size,
                              hipStream_t stream) {
  const float* x = (const float*)d_in[0];
  const float* w_in = (const float*)d_in[1];
  const float* w_out = (const float*)d_in[2];
  const float* w_fc = (const float*)d_in[3];
  const float* b_fc = (const float*)d_in[4];
  const float* w_proj = (const float*)d_in[5];
  const float* b_proj = (const float*)d_in[6];
  float* out = (float*)d_out;

  char* ws = (char*)d_ws;
  unsigned short* w_in_b = (unsigned short*)(ws);                  // 0-6MB
  unsigned short* w_out_b = (unsigned short*)(ws + 6291456);       // 6-8MB
  unsigned short* w_fc_b = (unsigned short*)(ws + 8388608);        // 8-16MB
  unsigned short* w_proj_b = (unsigned short*)(ws + 16777216);     // 16-24MB
  unsigned short* h_b = (unsigned short*)(ws + 25165824);          // 24-32MB (ln1, ln2)
  float* x2 = (float*)(ws + 33554432);                             // 32-48MB
  unsigned short* qkv_b = (unsigned short*)(ws + 50331648);        // 48-72MB
  unsigned short* o_b = (unsigned short*)(ws + 75497472);          // 72-80MB
  unsigned short* m_b = (unsigned short*)(ws + 50331648);          // 48-80MB alias (dead qkv+o)
  unsigned short* Kp = (unsigned short*)(ws + 83886080);           // 80-88MB
  unsigned short* Vp = (unsigned short*)(ws + 92274688);           // 88-96MB

  f2b_all<<<12288, 256, 0, stream>>>(w_in, w_out, w_fc, w_proj,
                                     w_in_b, w_out_b, w_fc_b, w_proj_b);

  // ln1: h = LN(x), and pre-init x2 := x for the w_out split-K atomics
  ln_kernel<<<4096, 256, 0, stream>>>(x, h_b, x2, nullptr);

  // qkv = h @ w_in^T : [4096,3072] bf16.  BN=192 -> 16 bn, grid 512
  gemm_bt<0, 192, 1><<<512, 256, 0, stream>>>(h_b, w_in_b, 4096, 3072, 1024,
                                              nullptr, nullptr, qkv_b);

  pack_kv<<<1024, 256, 0, stream>>>(qkv_b, Kp, Vp);

  attn_kernel<<<1024, 256, 0, stream>>>(qkv_b, Kp, Vp, o_b);

  // x2 += o @ w_out^T  (split-K4 atomic, BN=256: 4 bn x 4 kz, grid 512)
  gemm_bt<4, 256, 4><<<512, 256, 0, stream>>>(o_b, w_out_b, 4096, 1024, 1024,
                                              nullptr, x2, nullptr);

  // ln2: h2 = LN(x2), and pre-init out := x2 + b_proj for proj atomics
  ln_kernel<<<4096, 256, 0, stream>>>(x2, h_b, out, b_proj);

  // m = relu(h2 @ w_fc^T + b_fc) : [4096,4096] bf16.  BN=256 -> 16 bn, grid 512
  gemm_bt<2, 256, 1><<<512, 256, 0, stream>>>(h_b, w_fc_b, 4096, 4096, 1024,
                                              b_fc, nullptr, m_b);

  // out += m @ w_proj^T  (split-K4 atomic, grid 512)
  gemm_bt<4, 256, 4><<<512, 256, 0, stream>>>(m_b, w_proj_b, 4096, 1024, 4096,
                                              nullptr, out, nullptr);
}

// Round 8
// 338.051 us; speedup vs baseline: 1.1840x; 1.1840x over previous
//
#include <hip/hip_runtime.h>
#include <stdint.h>

#define AS1 __attribute__((address_space(1)))
#define AS3 __attribute__((address_space(3)))

typedef __bf16 bf8_t __attribute__((ext_vector_type(8)));
typedef float f4_t __attribute__((ext_vector_type(4)));
typedef unsigned short ush;

// ---------------- helpers ----------------
__device__ __forceinline__ ush f2b(float f) {
  unsigned u = __builtin_bit_cast(unsigned, f);
  u += 0x7fffu + ((u >> 16) & 1u);          // RNE
  return (ush)(u >> 16);
}
__device__ __forceinline__ void unpack8(uint4 u, float* dst) {
  unsigned a0 = u.x, a1 = u.y, a2 = u.z, a3 = u.w;
  dst[0] = __builtin_bit_cast(float, a0 << 16);
  dst[1] = __builtin_bit_cast(float, a0 & 0xffff0000u);
  dst[2] = __builtin_bit_cast(float, a1 << 16);
  dst[3] = __builtin_bit_cast(float, a1 & 0xffff0000u);
  dst[4] = __builtin_bit_cast(float, a2 << 16);
  dst[5] = __builtin_bit_cast(float, a2 & 0xffff0000u);
  dst[6] = __builtin_bit_cast(float, a3 << 16);
  dst[7] = __builtin_bit_cast(float, a3 & 0xffff0000u);
}

// ---------------- fused f32 -> bf16 convert for all 4 weights -------------
__global__ __launch_bounds__(256) void f2b_all(
    const float* __restrict__ w_in, const float* __restrict__ w_out,
    const float* __restrict__ w_fc, const float* __restrict__ w_proj,
    ush* __restrict__ o_in, ush* __restrict__ o_out,
    ush* __restrict__ o_fc, ush* __restrict__ o_proj) {
  const int blk = blockIdx.x;
  const float* src;
  ush* dst;
  int base;
  if (blk < 3072) { src = w_in; dst = o_in; base = blk; }
  else if (blk < 4096) { src = w_out; dst = o_out; base = blk - 3072; }
  else if (blk < 8192) { src = w_fc; dst = o_fc; base = blk - 4096; }
  else { src = w_proj; dst = o_proj; base = blk - 8192; }
  const int i = (base * 256 + threadIdx.x) * 4;
  float4 v = *(const float4*)(src + i);
  union { ush u[4]; uint2 d; } p;
  p.u[0] = f2b(v.x); p.u[1] = f2b(v.y); p.u[2] = f2b(v.z); p.u[3] = f2b(v.w);
  *(uint2*)(dst + i) = p.d;
}

// ---------------- LayerNorm (E=1024), f32 in -> bf16 out ----------------
__global__ __launch_bounds__(256) void ln_kernel(const float* __restrict__ x,
                                                 ush* __restrict__ out) {
  const int row = blockIdx.x, tid = threadIdx.x;
  const float* xr = x + (size_t)row * 1024;
  float4 v = ((const float4*)xr)[tid];
  float s = v.x + v.y + v.z + v.w;
  float q = v.x * v.x + v.y * v.y + v.z * v.z + v.w * v.w;
  for (int o = 32; o; o >>= 1) { s += __shfl_down(s, o); q += __shfl_down(q, o); }
  __shared__ float rs[4], rq[4];
  const int w = tid >> 6;
  if ((tid & 63) == 0) { rs[w] = s; rq[w] = q; }
  __syncthreads();
  s = rs[0] + rs[1] + rs[2] + rs[3];
  q = rq[0] + rq[1] + rq[2] + rq[3];
  const float mean = s * (1.0f / 1024.0f);
  const float var = q * (1.0f / 1024.0f) - mean * mean;
  const float rstd = rsqrtf(var + 1e-5f);
  union { ush u[4]; uint2 d; } p;
  p.u[0] = f2b((v.x - mean) * rstd);
  p.u[1] = f2b((v.y - mean) * rstd);
  p.u[2] = f2b((v.z - mean) * rstd);
  p.u[3] = f2b((v.w - mean) * rstd);
  *(uint2*)(out + (size_t)row * 1024 + tid * 4) = p.d;
}

// ---------------- GEMM: C[M,N] = A[M,K] @ W[N,K]^T (bf16 in, fp32 acc) ------
// BM x 128 tile, double-buffered global_load_lds, 1 barrier/K-iter.
// bf16 epilogues (EPI 0/2) bounce the C-tile through LDS -> coalesced
// dwordx4 stores (the old per-element 2B stores left 32MB of partial dirty
// lines in L2 for the consumer GEMM to choke on).
// EPI: 0 = bf16; 1 = +resid f32; 2 = +bias relu bf16; 3 = +bias +resid f32
template <int EPI, int BM, int MINW>
__global__ __launch_bounds__(256, MINW) void gemm_bt(
    const ush* __restrict__ A, const ush* __restrict__ Bw,
    int M, int N, int K,
    const float* __restrict__ bias, const float* __restrict__ resid,
    float* __restrict__ outF, ush* __restrict__ outB) {
  constexpr int MI = BM / 32;           // m-frags per wave
  constexpr int NCH = (BM + 128) / 16;  // staging chunks per k-tile
  constexpr int PC = NCH / 4;           // chunks per wave
  constexpr int ASZ = BM * 32;          // shorts per A buffer
  __shared__ ush lds[2 * ASZ + 2 * 4096];
  const int tid = threadIdx.x;
  const int wave = tid >> 6, lane = tid & 63;
  const int bm = blockIdx.x, bn = blockIdx.y;
  const int wm = (wave & 1) * (BM / 2), wn = (wave >> 1) * 64;
  const int l16 = lane & 15, quad = lane >> 4;
  const int srow = lane >> 2;
  const int scol = (lane & 3) * 8;

  const ush* Abase = A + (size_t)(bm * BM) * K;
  const ush* Bbase = Bw + (size_t)(bn * 128) * K;

  f4_t acc[MI][4];
#pragma unroll
  for (int i = 0; i < MI; ++i)
#pragma unroll
    for (int j = 0; j < 4; ++j) acc[i][j] = (f4_t){0.f, 0.f, 0.f, 0.f};

  const int kiters = K >> 5;

  auto stage = [&](int k0, int buf) {
    const int kk = k0 * 32;
#pragma unroll
    for (int i = 0; i < PC; ++i) {
      const int c = wave * PC + i;
      if (c < BM / 16) {
        const ush* ga = Abase + (size_t)(c * 16 + srow) * K + kk + scol;
        __builtin_amdgcn_global_load_lds((const AS1 void*)ga,
                                         (AS3 void*)(lds + buf * ASZ + c * 512), 16, 0, 0);
      } else {
        const int c2 = c - BM / 16;
        const ush* gb = Bbase + (size_t)(c2 * 16 + srow) * K + kk + scol;
        __builtin_amdgcn_global_load_lds(
            (const AS1 void*)gb, (AS3 void*)(lds + 2 * ASZ + buf * 4096 + c2 * 512), 16, 0, 0);
      }
    }
  };

  stage(0, 0);
  __syncthreads();
  for (int k0 = 0; k0 < kiters; ++k0) {
    const int cur = k0 & 1;
    if (k0 + 1 < kiters) stage(k0 + 1, cur ^ 1);
    bf8_t af[MI], bfr[4];
#pragma unroll
    for (int mi = 0; mi < MI; ++mi)
      af[mi] = *(const bf8_t*)&lds[cur * ASZ + (wm + mi * 16 + l16) * 32 + quad * 8];
#pragma unroll
    for (int ni = 0; ni < 4; ++ni)
      bfr[ni] = *(const bf8_t*)&lds[2 * ASZ + cur * 4096 + (wn + ni * 16 + l16) * 32 + quad * 8];
#pragma unroll
    for (int mi = 0; mi < MI; ++mi)
#pragma unroll
      for (int ni = 0; ni < 4; ++ni)
        acc[mi][ni] =
            __builtin_amdgcn_mfma_f32_16x16x32_bf16(af[mi], bfr[ni], acc[mi][ni], 0, 0, 0);
    __syncthreads();  // drains next-tile loads (issued a full compute phase ago)
  }

  if (EPI == 0 || EPI == 2) {
    // ---- coalesced bf16 epilogue: bounce C-tile through wave-private LDS ----
    ush* eb = lds + wave * ASZ;  // (BM/2) x 64 shorts, wave-private
#pragma unroll
    for (int mi = 0; mi < MI; ++mi)
#pragma unroll
      for (int ni = 0; ni < 4; ++ni) {
        const int gn = bn * 128 + wn + ni * 16 + l16;
        const float bv = (EPI == 2) ? bias[gn] : 0.0f;
#pragma unroll
        for (int r = 0; r < 4; ++r) {
          float v = acc[mi][ni][r] + bv;
          if (EPI == 2) v = fmaxf(v, 0.0f);
          eb[(mi * 16 + quad * 4 + r) * 64 + ni * 16 + l16] = f2b(v);
        }
      }
#pragma unroll
    for (int j = 0; j < BM / 16; ++j) {
      const int lr = j * 8 + (lane >> 3);
      const int c8 = (lane & 7) * 8;
      uint4 v = *(const uint4*)&eb[lr * 64 + c8];
      *(uint4*)(outB + (size_t)(bm * BM + wm + lr) * N + bn * 128 + wn + c8) = v;
    }
  } else {
#pragma unroll
    for (int mi = 0; mi < MI; ++mi) {
#pragma unroll
      for (int ni = 0; ni < 4; ++ni) {
        const int gm0 = bm * BM + wm + mi * 16 + quad * 4;
        const int gn = bn * 128 + wn + ni * 16 + l16;
        const float bv = (EPI == 3) ? bias[gn] : 0.0f;
#pragma unroll
        for (int r = 0; r < 4; ++r) {
          const size_t idx = (size_t)(gm0 + r) * N + gn;
          outF[idx] = acc[mi][ni][r] + bv + resid[idx];
        }
      }
    }
  }
}

// ---------------- K/V tile pre-pack ----------------
__global__ __launch_bounds__(256) void pack_kv(const ush* __restrict__ qkv,
                                               ush* __restrict__ Kp,
                                               ush* __restrict__ Vp) {
  const int lin = blockIdx.x;
  const int kt = lin & 31, h = (lin >> 5) & 15, b = lin >> 9;
  const int tid = threadIdx.x;
  __shared__ ush Vs[64 * 72];
  const size_t rowbase = (size_t)(b * 2048 + kt * 64) * 3072 + h * 64;
  ush* Kt = Kp + (size_t)lin * 4096;
  ush* Vt = Vp + (size_t)lin * 4096;

  const int r0 = tid >> 3, cin = tid & 7;
#pragma unroll
  for (int it = 0; it < 2; ++it) {
    const int r = r0 + it * 32;
    uint4 ku = *(const uint4*)(qkv + rowbase + (size_t)r * 3072 + 1024 + cin * 8);
    float f[8]; unpack8(ku, f);
    union { ush us[8]; uint4 v; } pk;
#pragma unroll
    for (int j = 0; j < 8; ++j) pk.us[j] = f2b(f[j] * 0.125f);
    *(uint4*)(Kt + (size_t)(r * 8 + (cin ^ (r & 7))) * 8) = pk.v;
    uint4 vu = *(const uint4*)(qkv + rowbase + (size_t)r * 3072 + 2048 + cin * 8);
    *(uint4*)&Vs[r * 72 + cin * 8] = vu;
  }
  __syncthreads();
#pragma unroll
  for (int oc2 = 0; oc2 < 2; ++oc2) {
    const int oc = tid * 2 + oc2;
    const int d = oc >> 3, c = oc & 7;
    const int k0 = 8 * (c ^ (d & 7));
    union { ush us[8]; uint4 v; } pk;
#pragma unroll
    for (int j = 0; j < 8; ++j) pk.us[j] = Vs[(k0 + j) * 72 + d];
    *(uint4*)(Vt + (size_t)oc * 8) = pk.v;
  }
}

// ---------------- MFMA causal flash attention ----------------
__global__ __launch_bounds__(256, 4) void attn_kernel(const ush* __restrict__ qkv,
                                                      const ush* __restrict__ Kp,
                                                      const ush* __restrict__ Vp,
                                                      ush* __restrict__ o) {
  const int lin = blockIdx.x;
  const int b = lin & 1, h = (lin >> 1) & 15, tq = lin >> 5;
  const int tid = threadIdx.x;
  const int wave = tid >> 6, lane = tid & 63;
  const int l15 = lane & 15, quad = lane >> 4;

  __shared__ __align__(16) ush Ks[64 * 64];
  __shared__ __align__(16) ush Vt[64 * 64];
  __shared__ __align__(16) ush Ps[64 * 72];

  bf8_t qf[2];
  {
    const int qrow = b * 2048 + tq * 64 + wave * 16 + l15;
#pragma unroll
    for (int s = 0; s < 2; ++s) {
      union { uint4 u; bf8_t v; } pk;
      pk.u = *(const uint4*)(qkv + (size_t)qrow * 3072 + h * 64 + s * 32 + quad * 8);
      qf[s] = pk.v;
    }
  }

  float m_s = -1e30f, l_s = 0.f;
  f4_t O[4];
#pragma unroll
  for (int j = 0; j < 4; ++j) O[j] = (f4_t){0.f, 0.f, 0.f, 0.f};

  const int qw0 = tq * 64 + wave * 16;
  const int swz = (l15 & 7) * 8;
  const size_t tile0 = (size_t)((b * 16 + h) * 32) * 4096;

  for (int kt = 0; kt <= tq; ++kt) {
    __syncthreads();
    const ush* Ktile = Kp + tile0 + (size_t)kt * 4096;
    const ush* Vtile = Vp + tile0 + (size_t)kt * 4096;
#pragma unroll
    for (int i = 0; i < 2; ++i) {
      const int seg = wave * 2 + i;
      __builtin_amdgcn_global_load_lds((const AS1 void*)(Ktile + seg * 512 + lane * 8),
                                       (AS3 void*)(Ks + seg * 512), 16, 0, 0);
      __builtin_amdgcn_global_load_lds((const AS1 void*)(Vtile + seg * 512 + lane * 8),
                                       (AS3 void*)(Vt + seg * 512), 16, 0, 0);
    }
    __syncthreads();

    f4_t S[4];
#pragma unroll
    for (int mi = 0; mi < 4; ++mi) S[mi] = (f4_t){0.f, 0.f, 0.f, 0.f};
#pragma unroll
    for (int s = 0; s < 2; ++s)
#pragma unroll
      for (int mi = 0; mi < 4; ++mi) {
        bf8_t kf = *(const bf8_t*)&Ks[(mi * 16 + l15) * 64 + (((4 * s + quad) * 8) ^ swz)];
        S[mi] = __builtin_amdgcn_mfma_f32_16x16x32_bf16(kf, qf[s], S[mi], 0, 0, 0);
      }

    if (kt == tq) {
#pragma unroll
      for (int mi = 0; mi < 4; ++mi)
#pragma unroll
        for (int r = 0; r < 4; ++r) {
          const int kg = kt * 64 + mi * 16 + quad * 4 + r;
          const int qg = qw0 + l15;
          if (kg > qg) S[mi][r] = -1e30f;
        }
    }

    float mx = -1e30f;
#pragma unroll
    for (int mi = 0; mi < 4; ++mi)
#pragma unroll
      for (int r = 0; r < 4; ++r) mx = fmaxf(mx, S[mi][r]);
    mx = fmaxf(mx, __shfl_xor(mx, 16));
    mx = fmaxf(mx, __shfl_xor(mx, 32));
    const float mn = fmaxf(m_s, mx);
    const float alpha = __expf(m_s - mn);
    float sum = 0.f;
#pragma unroll
    for (int mi = 0; mi < 4; ++mi)
#pragma unroll
      for (int r = 0; r < 4; ++r) {
        const float p = __expf(S[mi][r] - mn);
        S[mi][r] = p;
        sum += p;
      }
    sum += __shfl_xor(sum, 16);
    sum += __shfl_xor(sum, 32);
    m_s = mn;
    l_s = l_s * alpha + sum;
#pragma unroll
    for (int mi = 0; mi < 4; ++mi) {
      uint2 w2;
      w2.x = (unsigned)f2b(S[mi][0]) | ((unsigned)f2b(S[mi][1]) << 16);
      w2.y = (unsigned)f2b(S[mi][2]) | ((unsigned)f2b(S[mi][3]) << 16);
      *(uint2*)&Ps[(wave * 16 + l15) * 72 + mi * 16 + quad * 4] = w2;
    }

    bf8_t pf[2], vf[4][2];
#pragma unroll
    for (int s = 0; s < 2; ++s)
      pf[s] = *(const bf8_t*)&Ps[(wave * 16 + l15) * 72 + s * 32 + quad * 8];
#pragma unroll
    for (int n4 = 0; n4 < 4; ++n4)
#pragma unroll
      for (int s = 0; s < 2; ++s)
        vf[n4][s] = *(const bf8_t*)&Vt[(n4 * 16 + l15) * 64 + (((4 * s + quad) * 8) ^ swz)];
    float ar[4];
#pragma unroll
    for (int r = 0; r < 4; ++r) ar[r] = __shfl(alpha, quad * 4 + r);
#pragma unroll
    for (int n4 = 0; n4 < 4; ++n4) {
#pragma unroll
      for (int r = 0; r < 4; ++r) O[n4][r] *= ar[r];
#pragma unroll
      for (int s = 0; s < 2; ++s)
        O[n4] = __builtin_amdgcn_mfma_f32_16x16x32_bf16(pf[s], vf[n4][s], O[n4], 0, 0, 0);
    }
  }

  const float rc = 1.0f / l_s;
  float rr[4];
#pragma unroll
  for (int r = 0; r < 4; ++r) rr[r] = __shfl(rc, quad * 4 + r);
#pragma unroll
  for (int n4 = 0; n4 < 4; ++n4)
#pragma unroll
    for (int r = 0; r < 4; ++r) {
      const int qg = tq * 64 + wave * 16 + quad * 4 + r;
      o[(size_t)(b * 2048 + qg) * 1024 + h * 64 + n4 * 16 + l15] = f2b(O[n4][r] * rr[r]);
    }
}

// ---------------- launcher ----------------
extern "C" void kernel_launch(void* const* d_in, const int* in_sizes, int n_in,
                              void* d_out, int out_size, void* d_ws, size_t ws_size,
                              hipStream_t stream) {
  const float* x = (const float*)d_in[0];
  const float* w_in = (const float*)d_in[1];
  const float* w_out = (const float*)d_in[2];
  const float* w_fc = (const float*)d_in[3];
  const float* b_fc = (const float*)d_in[4];
  const float* w_proj = (const float*)d_in[5];
  const float* b_proj = (const float*)d_in[6];
  float* out = (float*)d_out;

  char* ws = (char*)d_ws;
  ush* w_in_b = (ush*)(ws);                  // 0-6MB
  ush* w_out_b = (ush*)(ws + 6291456);       // 6-8MB
  ush* w_fc_b = (ush*)(ws + 8388608);        // 8-16MB
  ush* w_proj_b = (ush*)(ws + 16777216);     // 16-24MB
  ush* h_b = (ush*)(ws + 25165824);          // 24-32MB (ln1, ln2)
  float* x2 = (float*)(ws + 33554432);       // 32-48MB
  ush* qkv_b = (ush*)(ws + 50331648);        // 48-72MB
  ush* o_b = (ush*)(ws + 75497472);          // 72-80MB
  ush* m_b = (ush*)(ws + 50331648);          // 48-80MB alias (dead qkv+o)
  ush* Kp = (ush*)(ws + 83886080);           // 80-88MB
  ush* Vp = (ush*)(ws + 92274688);           // 88-96MB

  f2b_all<<<12288, 256, 0, stream>>>(w_in, w_out, w_fc, w_proj,
                                     w_in_b, w_out_b, w_fc_b, w_proj_b);

  ln_kernel<<<4096, 256, 0, stream>>>(x, h_b);

  // qkv = h @ w_in^T : [4096,3072] bf16, coalesced epilogue
  gemm_bt<0, 128, 2><<<dim3(32, 24), 256, 0, stream>>>(
      h_b, w_in_b, 4096, 3072, 1024, nullptr, nullptr, nullptr, qkv_b);

  pack_kv<<<1024, 256, 0, stream>>>(qkv_b, Kp, Vp);

  attn_kernel<<<1024, 256, 0, stream>>>(qkv_b, Kp, Vp, o_b);

  // x2 = x + o @ w_out^T : f32
  gemm_bt<1, 64, 4><<<dim3(64, 8), 256, 0, stream>>>(
      o_b, w_out_b, 4096, 1024, 1024, nullptr, x, x2, nullptr);

  ln_kernel<<<4096, 256, 0, stream>>>(x2, h_b);

  // m = relu(h2 @ w_fc^T + b_fc) : [4096,4096] bf16, coalesced epilogue
  gemm_bt<2, 128, 2><<<dim3(32, 32), 256, 0, stream>>>(
      h_b, w_fc_b, 4096, 4096, 1024, b_fc, nullptr, nullptr, m_b);

  // out = x2 + b_proj + m @ w_proj^T : f32
  gemm_bt<3, 64, 4><<<dim3(64, 8), 256, 0, stream>>>(
      m_b, w_proj_b, 4096, 1024, 4096, b_proj, x2, out, nullptr);
}